// Round 3
// baseline (367.510 us; speedup 1.0000x reference)
//
#include <hip/hip_runtime.h>
#include <hip/hip_bf16.h>
#include <stdint.h>

#define B_   8
#define L_   2048
#define D_   256
#define H_   256

typedef short bf16x8 __attribute__((ext_vector_type(8)));
typedef float f32x4  __attribute__((ext_vector_type(4)));

#define MFMA(a,b,c) __builtin_amdgcn_mfma_f32_16x16x32_bf16(a,b,c,0,0,0)

__device__ __forceinline__ unsigned short f2bf(float f){
  __hip_bfloat16 h = __float2bfloat16(f);
  unsigned short us;
  __builtin_memcpy(&us, &h, 2);
  return us;
}

// ---------------- weight norm: w[h,:] = g[h] * v[h,:] / ||v[h,:]|| -> bf16
__global__ __launch_bounds__(256) void wnorm_kernel(const float* __restrict__ v,
                                                    const float* __restrict__ g,
                                                    unsigned short* __restrict__ w){
  int h = blockIdx.x;
  int d = threadIdx.x;
  float x = v[h*D_ + d];
  float sq = x*x;
  for (int off = 32; off; off >>= 1) sq += __shfl_down(sq, off, 64);
  __shared__ float red[4];
  int lane = threadIdx.x & 63, wid = threadIdx.x >> 6;
  if (lane == 0) red[wid] = sq;
  __syncthreads();
  float tot = red[0] + red[1] + red[2] + red[3];
  float scale = g[h] / sqrtf(tot);
  w[h*D_ + d] = f2bf(x * scale);
}

// ---------------- transpose+convert: x [B][L][D] f32 -> xT [B][D][L] bf16
__global__ __launch_bounds__(256) void transpose_kernel(const float* __restrict__ x,
                                                        unsigned short* __restrict__ xT){
  __shared__ float tile[32][33];
  int bz = blockIdx.z;
  int l0 = blockIdx.x * 32;
  int d0 = blockIdx.y * 32;
  int tx = threadIdx.x, ty = threadIdx.y; // (32,8)
  const float* xp = x + (size_t)bz * L_ * D_;
  for (int k = 0; k < 4; k++)
    tile[ty + 8*k][tx] = xp[(size_t)(l0 + ty + 8*k) * D_ + d0 + tx];
  __syncthreads();
  unsigned short* op = xT + (size_t)bz * D_ * L_;
  for (int k = 0; k < 4; k++)
    op[(size_t)(d0 + ty + 8*k) * L_ + l0 + tx] = f2bf(tile[tx][ty + 8*k]);
}

// ---------------- hx = bf16(scale * relu(x @ w^T + bias));  x:[M][256] f32, w:[256][256] bf16
__global__ __launch_bounds__(256) void hgemm_kernel(const float* __restrict__ x,
      const unsigned short* __restrict__ w, const float* __restrict__ bias,
      const float* __restrict__ tau_ptr, int apply_tau,
      unsigned short* __restrict__ hx){
  int m0 = blockIdx.x * 64;
  int c0 = blockIdx.y * 64;
  int lane = threadIdx.x & 63, wid = threadIdx.x >> 6;
  int row = m0 + wid*16 + (lane & 15);
  int kb  = (lane >> 4) * 8;
  float scale = apply_tau ? tau_ptr[0] : 1.0f;
  f32x4 acc[4] = {};
  for (int kk = 0; kk < 8; kk++){
    const float* ap = x + (size_t)row * 256 + kk*32 + kb;
    f32x4 a0 = *(const f32x4*)ap;
    f32x4 a1 = *(const f32x4*)(ap + 4);
    bf16x8 af;
    af[0]=(short)f2bf(a0[0]); af[1]=(short)f2bf(a0[1]); af[2]=(short)f2bf(a0[2]); af[3]=(short)f2bf(a0[3]);
    af[4]=(short)f2bf(a1[0]); af[5]=(short)f2bf(a1[1]); af[6]=(short)f2bf(a1[2]); af[7]=(short)f2bf(a1[3]);
    for (int n = 0; n < 4; n++){
      int col = c0 + n*16 + (lane & 15);
      bf16x8 bfr = *(const bf16x8*)(w + (size_t)col * 256 + kk*32 + kb);
      acc[n] = MFMA(af, bfr, acc[n]);
    }
  }
  for (int n = 0; n < 4; n++){
    int col = c0 + n*16 + (lane & 15);
    float bv = bias[col];
    for (int r = 0; r < 4; r++){
      int orow = m0 + wid*16 + (lane >> 4)*4 + r;
      float vv = acc[n][r] + bv;
      vv = vv > 0.f ? vv : 0.f;
      hx[(size_t)orow * 256 + col] = f2bf(vv * scale);
    }
  }
}

// ---------------- fused flash alignment:
// dir 0: out_a[i,:] = softmax_j(ha@hb^T + maskb_j) @ b     (vT = bT)
// dir 1: out_b[j,:] = softmax_i(hb@ha^T + maska_i) @ a     (vT = aT)
// Flat 1024-block grid; s = bid&15 keeps each (dir,bz) stream on one XCD
// (2 streams x ~2MB per XCD L2). Block: 32 rows, 2 waves; wave w handles
// j in [w*1024, w*1024+1024); online softmax w/ defer-rescale; 2-way merge.
__global__ __launch_bounds__(128, 2) void flash_kernel(
    const unsigned short* __restrict__ ha, const unsigned short* __restrict__ hb,
    const unsigned short* __restrict__ aT, const unsigned short* __restrict__ bT,
    const int* __restrict__ mask_a, const int* __restrict__ mask_b,
    float* __restrict__ out)
{
  __shared__ __align__(16) unsigned short wtile[2][32][40];  // padded: 80B rows
  __shared__ float mstat[2][32];
  __shared__ float sstat[2][32];
  __shared__ float accbuf[32][256];

  const int bid = blockIdx.x;
  const int s   = bid & 15;
  const int dir = s >> 3;
  const int bz  = s & 7;
  const int i0  = (bid >> 4) * 32;
  const int lane = threadIdx.x & 63;
  const int wid  = threadIdx.x >> 6;
  const int p = lane & 15, q = lane >> 4;
  const int kb = q * 8;

  const unsigned short* hA = dir ? hb : ha;
  const unsigned short* hB = dir ? ha : hb;
  const unsigned short* vT = dir ? aT : bT;
  const int* mask = dir ? mask_a : mask_b;
  float* outp = out + ((size_t)dir * B_ + bz) * L_ * D_;

  const unsigned short* hAp = hA + (size_t)bz * L_ * H_;
  const unsigned short* hBp = hB + (size_t)bz * L_ * H_;
  const unsigned short* vTp = vT + (size_t)bz * D_ * L_;
  const int* mp = mask + bz * L_;

  bf16x8 af[2][8];
  #pragma unroll
  for (int G = 0; G < 2; ++G)
    #pragma unroll
    for (int kk = 0; kk < 8; ++kk)
      af[G][kk] = *(const bf16x8*)(hAp + (size_t)(i0 + G*16 + p) * H_ + kk*32 + kb);

  f32x4 acc[2][16];
  #pragma unroll
  for (int G = 0; G < 2; ++G)
    #pragma unroll
    for (int n = 0; n < 16; ++n)
      acc[G][n] = (f32x4){0.f, 0.f, 0.f, 0.f};

  float m_run[2][4], s_run[2][4];
  #pragma unroll
  for (int G = 0; G < 2; ++G)
    #pragma unroll
    for (int r = 0; r < 4; ++r){ m_run[G][r] = -1e30f; s_run[G][r] = 0.f; }

  const int jbase = wid * (L_ / 2);
  for (int jt = 0; jt < (L_/2)/32; ++jt){
    const int j0 = jbase + jt*32;
    // ---- P = hA[i0:i0+32] @ hB[j0:j0+32]^T  (K = 256)
    f32x4 accp[2][2];
    #pragma unroll
    for (int G = 0; G < 2; ++G)
      #pragma unroll
      for (int n = 0; n < 2; ++n)
        accp[G][n] = (f32x4){0.f, 0.f, 0.f, 0.f};
    __builtin_amdgcn_s_setprio(1);
    #pragma unroll
    for (int kk = 0; kk < 8; ++kk){
      bf16x8 b0 = *(const bf16x8*)(hBp + (size_t)(j0 + p)      * H_ + kk*32 + kb);
      bf16x8 b1 = *(const bf16x8*)(hBp + (size_t)(j0 + 16 + p) * H_ + kk*32 + kb);
      accp[0][0] = MFMA(af[0][kk], b0, accp[0][0]);
      accp[1][0] = MFMA(af[1][kk], b0, accp[1][0]);
      accp[0][1] = MFMA(af[0][kk], b1, accp[0][1]);
      accp[1][1] = MFMA(af[1][kk], b1, accp[1][1]);
    }
    __builtin_amdgcn_s_setprio(0);
    // ---- mask + tile max
    float mt0 = (mp[j0 + p]      > 0) ? 0.f : -1e9f;
    float mt1 = (mp[j0 + 16 + p] > 0) ? 0.f : -1e9f;
    float tmax[2][4];
    #pragma unroll
    for (int G = 0; G < 2; ++G)
      #pragma unroll
      for (int r = 0; r < 4; ++r){
        accp[G][0][r] += mt0;
        accp[G][1][r] += mt1;
        tmax[G][r] = fmaxf(accp[G][0][r], accp[G][1][r]);
      }
    #pragma unroll
    for (int off = 1; off < 16; off <<= 1)
      #pragma unroll
      for (int G = 0; G < 2; ++G)
        #pragma unroll
        for (int r = 0; r < 4; ++r)
          tmax[G][r] = fmaxf(tmax[G][r], __shfl_xor(tmax[G][r], off, 64));
    // ---- online update with defer-rescale (THR = 8)
    int need = 0;
    #pragma unroll
    for (int G = 0; G < 2; ++G)
      #pragma unroll
      for (int r = 0; r < 4; ++r)
        need |= (tmax[G][r] > m_run[G][r] + 8.f) ? 1 : 0;
    if (__any(need)){
      float fsc[2][4];
      #pragma unroll
      for (int G = 0; G < 2; ++G)
        #pragma unroll
        for (int r = 0; r < 4; ++r){
          float mn = fmaxf(m_run[G][r], tmax[G][r]);
          fsc[G][r] = __expf(m_run[G][r] - mn);
          s_run[G][r] *= fsc[G][r];
          m_run[G][r] = mn;
        }
      #pragma unroll
      for (int G = 0; G < 2; ++G)
        #pragma unroll
        for (int n = 0; n < 16; ++n)
          #pragma unroll
          for (int r = 0; r < 4; ++r)
            acc[G][n][r] *= fsc[G][r];
    }
    // ---- weights -> bf16 -> LDS (per-wave tile, no barrier needed)
    #pragma unroll
    for (int G = 0; G < 2; ++G)
      #pragma unroll
      for (int n = 0; n < 2; ++n)
        #pragma unroll
        for (int r = 0; r < 4; ++r){
          float w = __expf(accp[G][n][r] - m_run[G][r]);
          s_run[G][r] += w;
          wtile[wid][G*16 + q*4 + r][n*16 + p] = f2bf(w);
        }
    asm volatile("s_waitcnt lgkmcnt(0)" ::: "memory");
    bf16x8 wf0 = *(const bf16x8*)(&wtile[wid][p][kb]);
    bf16x8 wf1 = *(const bf16x8*)(&wtile[wid][16 + p][kb]);
    // ---- PV: acc += W @ V  (V as vT [D][L])
    __builtin_amdgcn_s_setprio(1);
    #pragma unroll
    for (int n = 0; n < 16; ++n){
      bf16x8 vf = *(const bf16x8*)(vTp + (size_t)(n*16 + p) * L_ + j0 + kb);
      acc[0][n] = MFMA(wf0, vf, acc[0][n]);
      acc[1][n] = MFMA(wf1, vf, acc[1][n]);
    }
    __builtin_amdgcn_s_setprio(0);
  }

  // ---- reduce s over the 16 col-lanes
  #pragma unroll
  for (int off = 1; off < 16; off <<= 1)
    #pragma unroll
    for (int G = 0; G < 2; ++G)
      #pragma unroll
      for (int r = 0; r < 4; ++r)
        s_run[G][r] += __shfl_xor(s_run[G][r], off, 64);

  // ---- 2-way cross-wave merge
  if (p == 0){
    #pragma unroll
    for (int G = 0; G < 2; ++G)
      #pragma unroll
      for (int r = 0; r < 4; ++r){
        mstat[wid][G*16 + q*4 + r] = m_run[G][r];
        sstat[wid][G*16 + q*4 + r] = s_run[G][r];
      }
  }
  __syncthreads();
  float fac[2][4], invS[2][4];
  const int ow = wid ^ 1;
  #pragma unroll
  for (int G = 0; G < 2; ++G)
    #pragma unroll
    for (int r = 0; r < 4; ++r){
      int row = G*16 + q*4 + r;
      float mo = mstat[ow][row], so = sstat[ow][row];
      float M = fmaxf(m_run[G][r], mo);
      fac[G][r] = __expf(m_run[G][r] - M);
      float S = s_run[G][r] * fac[G][r] + so * __expf(mo - M);
      invS[G][r] = 1.0f / S;
    }
  if (wid == 1){
    #pragma unroll
    for (int G = 0; G < 2; ++G)
      #pragma unroll
      for (int n = 0; n < 16; ++n)
        #pragma unroll
        for (int r = 0; r < 4; ++r)
          accbuf[G*16 + q*4 + r][n*16 + p] = acc[G][n][r] * fac[G][r];
  }
  __syncthreads();
  if (wid == 0){
    #pragma unroll
    for (int G = 0; G < 2; ++G)
      #pragma unroll
      for (int n = 0; n < 16; ++n)
        #pragma unroll
        for (int r = 0; r < 4; ++r){
          int row = G*16 + q*4 + r, col = n*16 + p;
          outp[(size_t)(i0 + row) * D_ + col] =
              (acc[G][n][r] * fac[G][r] + accbuf[row][col]) * invS[G][r];
        }
  }
}

extern "C" void kernel_launch(void* const* d_in, const int* in_sizes, int n_in,
                              void* d_out, int out_size, void* d_ws, size_t ws_size,
                              hipStream_t stream) {
  const float* a      = (const float*)d_in[0];
  const float* b      = (const float*)d_in[1];
  const int*   mask_a = (const int*)d_in[2];
  const int*   mask_b = (const int*)d_in[3];
  const float* a_v    = (const float*)d_in[4];
  const float* a_g    = (const float*)d_in[5];
  const float* a_bias = (const float*)d_in[6];
  const float* b_v    = (const float*)d_in[7];
  const float* b_g    = (const float*)d_in[8];
  const float* b_bias = (const float*)d_in[9];
  const float* tau    = (const float*)d_in[10];

  float* out = (float*)d_out;

  char* ws = (char*)d_ws;
  const size_t SZ_W  = (size_t)H_ * D_ * 2;        // 128 KB
  const size_t SZ_H  = (size_t)B_ * L_ * H_ * 2;   // 8 MB
  unsigned short* wa = (unsigned short*)(ws);
  unsigned short* wb = (unsigned short*)(ws + SZ_W);
  unsigned short* ha = (unsigned short*)(ws + 2*SZ_W);
  unsigned short* hb = (unsigned short*)(ws + 2*SZ_W + SZ_H);
  unsigned short* aT = (unsigned short*)(ws + 2*SZ_W + 2*SZ_H);
  unsigned short* bT = (unsigned short*)(ws + 2*SZ_W + 3*SZ_H);
  size_t need = 2*SZ_W + 4*SZ_H;
  if (ws_size < need) return;

  // 1. normalized weights (bf16)
  wnorm_kernel<<<H_, 256, 0, stream>>>(a_v, a_g, wa);
  wnorm_kernel<<<H_, 256, 0, stream>>>(b_v, b_g, wb);

  // 2. transposed bf16 copies of a, b  ([B][D][L])
  {
    dim3 g(L_/32, D_/32, B_), blk(32, 8);
    transpose_kernel<<<g, blk, 0, stream>>>(a, aT);
    transpose_kernel<<<g, blk, 0, stream>>>(b, bT);
  }

  // 3. ha = bf16(tau*relu(a@wa^T + bias)), hb = bf16(relu(b@wb^T + bias))
  {
    dim3 g((B_*L_)/64, H_/64);
    hgemm_kernel<<<g, 256, 0, stream>>>(a, wa, a_bias, tau, 1, ha);
    hgemm_kernel<<<g, 256, 0, stream>>>(b, wb, b_bias, tau, 0, hb);
  }

  // 4. fused flash alignment, both directions in one launch (XCD-swizzled flat grid)
  {
    flash_kernel<<<dim3((L_/32) * B_ * 2), 128, 0, stream>>>(
        ha, hb, aT, bT, mask_a, mask_b, out);
  }
}

// Round 4
// 179.689 us; speedup vs baseline: 2.0453x; 2.0453x over previous
//
#include <hip/hip_runtime.h>
#include <hip/hip_bf16.h>
#include <stdint.h>

#define B_   8
#define L_   2048
#define D_   256
#define H_   256
#define TJ   64          // j-tile
#define NT   (L_/TJ)     // 32 tiles
#define BM   128         // rows per block
#define NWAVE 8

typedef short bf16x8 __attribute__((ext_vector_type(8)));
typedef float f32x4  __attribute__((ext_vector_type(4)));

#define MFMA(a,b,c) __builtin_amdgcn_mfma_f32_16x16x32_bf16(a,b,c,0,0,0)

typedef unsigned int u32;
__device__ __forceinline__ void gload_lds16(const void* g, void* l){
  __builtin_amdgcn_global_load_lds((const __attribute__((address_space(1))) u32*)g,
                                   (__attribute__((address_space(3))) u32*)l, 16, 0, 0);
}

__device__ __forceinline__ unsigned short f2bf(float f){
  __hip_bfloat16 h = __float2bfloat16(f);
  unsigned short us;
  __builtin_memcpy(&us, &h, 2);
  return us;
}

// ---------------- weight norm: w[h,:] = g[h] * v[h,:] / ||v[h,:]|| -> bf16
__global__ __launch_bounds__(256) void wnorm_kernel(const float* __restrict__ v,
                                                    const float* __restrict__ g,
                                                    unsigned short* __restrict__ w){
  int h = blockIdx.x;
  int d = threadIdx.x;
  float x = v[h*D_ + d];
  float sq = x*x;
  for (int off = 32; off; off >>= 1) sq += __shfl_down(sq, off, 64);
  __shared__ float red[4];
  int lane = threadIdx.x & 63, wid = threadIdx.x >> 6;
  if (lane == 0) red[wid] = sq;
  __syncthreads();
  float tot = red[0] + red[1] + red[2] + red[3];
  float scale = g[h] / sqrtf(tot);
  w[h*D_ + d] = f2bf(x * scale);
}

// ---------------- transpose+convert: x [B][L][D] f32 -> xT [B][D][L] bf16
__global__ __launch_bounds__(256) void transpose_kernel(const float* __restrict__ x,
                                                        unsigned short* __restrict__ xT){
  __shared__ float tile[32][33];
  int bz = blockIdx.z;
  int l0 = blockIdx.x * 32;
  int d0 = blockIdx.y * 32;
  int tx = threadIdx.x, ty = threadIdx.y; // (32,8)
  const float* xp = x + (size_t)bz * L_ * D_;
  for (int k = 0; k < 4; k++)
    tile[ty + 8*k][tx] = xp[(size_t)(l0 + ty + 8*k) * D_ + d0 + tx];
  __syncthreads();
  unsigned short* op = xT + (size_t)bz * D_ * L_;
  for (int k = 0; k < 4; k++)
    op[(size_t)(d0 + ty + 8*k) * L_ + l0 + tx] = f2bf(tile[tx][ty + 8*k]);
}

// ---------------- hx = bf16(scale * relu(x @ w^T + bias))
__global__ __launch_bounds__(256) void hgemm_kernel(const float* __restrict__ x,
      const unsigned short* __restrict__ w, const float* __restrict__ bias,
      const float* __restrict__ tau_ptr, int apply_tau,
      unsigned short* __restrict__ hx){
  int m0 = blockIdx.x * 64;
  int c0 = blockIdx.y * 64;
  int lane = threadIdx.x & 63, wid = threadIdx.x >> 6;
  int row = m0 + wid*16 + (lane & 15);
  int kb  = (lane >> 4) * 8;
  float scale = apply_tau ? tau_ptr[0] : 1.0f;
  f32x4 acc[4] = {};
  for (int kk = 0; kk < 8; kk++){
    const float* ap = x + (size_t)row * 256 + kk*32 + kb;
    f32x4 a0 = *(const f32x4*)ap;
    f32x4 a1 = *(const f32x4*)(ap + 4);
    bf16x8 af;
    af[0]=(short)f2bf(a0[0]); af[1]=(short)f2bf(a0[1]); af[2]=(short)f2bf(a0[2]); af[3]=(short)f2bf(a0[3]);
    af[4]=(short)f2bf(a1[0]); af[5]=(short)f2bf(a1[1]); af[6]=(short)f2bf(a1[2]); af[7]=(short)f2bf(a1[3]);
    for (int n = 0; n < 4; n++){
      int col = c0 + n*16 + (lane & 15);
      bf16x8 bfr = *(const bf16x8*)(w + (size_t)col * 256 + kk*32 + kb);
      acc[n] = MFMA(af, bfr, acc[n]);
    }
  }
  for (int n = 0; n < 4; n++){
    int col = c0 + n*16 + (lane & 15);
    float bv = bias[col];
    for (int r = 0; r < 4; r++){
      int orow = m0 + wid*16 + (lane >> 4)*4 + r;
      float vv = acc[n][r] + bv;
      vv = vv > 0.f ? vv : 0.f;
      hx[(size_t)orow * 256 + col] = f2bf(vv * scale);
    }
  }
}

// ---------------- fused flash alignment, LDS-staged + double-buffered.
// Block: 512 threads (8 waves), 128 output rows; wave w owns rows [w*16, w*16+16)
// over the FULL j range (no merge). Per 64-col tile: stage hB(64x256bf16) and
// vT(256x64bf16) into LDS via global_load_lds with pre-swizzled sources
// (slot ^= row&7); double-buffered (stage t+1, compute t, barrier).
__global__ __launch_bounds__(512, 2) void flash_kernel(
    const unsigned short* __restrict__ ha, const unsigned short* __restrict__ hb,
    const unsigned short* __restrict__ aT, const unsigned short* __restrict__ bT,
    const int* __restrict__ mask_a, const int* __restrict__ mask_b,
    float* __restrict__ out)
{
  __shared__ __align__(16) unsigned short hbt[2][64][256];   // 64 KB
  __shared__ __align__(16) unsigned short vtl[2][256][64];   // 64 KB
  __shared__ __align__(16) unsigned short wtile[NWAVE][16][80]; // 20 KB (pad 64->80)

  const int bid = blockIdx.x;
  const int s   = bid & 15;             // stream id; XCD = s&7 (bid%8==s%8)
  const int dir = s >> 3;
  const int bz  = s & 7;
  const int i0  = (bid >> 4) * BM;
  const int tid = threadIdx.x;
  const int lane = tid & 63;
  const int wid  = tid >> 6;
  const int p = lane & 15, q = lane >> 4;

  const unsigned short* hA = dir ? hb : ha;
  const unsigned short* hB = dir ? ha : hb;
  const unsigned short* vT = dir ? aT : bT;
  const int* mask = dir ? mask_a : mask_b;
  float* outp = out + ((size_t)dir * B_ + bz) * L_ * D_;

  const unsigned short* hAp = hA + (size_t)bz * L_ * H_;
  const unsigned short* hBp = hB + (size_t)bz * L_ * H_;
  const unsigned short* vTp = vT + (size_t)bz * D_ * L_;
  const int* mp = mask + bz * L_;

  // per-lane staging source geometry (constant across tiles except j0)
  // hbt: byte = k*8192 + wid*1024 + lane*16 -> row=k*16+wid*2+(lane>>5), slot=lane&31
  const int hb_r0 = wid*2 + (lane >> 5);      // + k*16
  const int hb_s  = lane & 31;
  // vtl: row = k*64 + wid*8 + lane/8, slot = lane&7
  const int vt_r0 = wid*8 + (lane >> 3);      // + k*64
  const int vt_s  = lane & 7;

  // A fragments: wave's 16 rows
  bf16x8 af[8];
  #pragma unroll
  for (int kk = 0; kk < 8; ++kk)
    af[kk] = *(const bf16x8*)(hAp + (size_t)(i0 + wid*16 + p) * H_ + kk*32 + q*8);

  f32x4 acc[16];
  #pragma unroll
  for (int n = 0; n < 16; ++n) acc[n] = (f32x4){0.f,0.f,0.f,0.f};
  float m_run[4], s_run[4];
  #pragma unroll
  for (int r = 0; r < 4; ++r){ m_run[r] = -1e30f; s_run[r] = 0.f; }

  // ---- stage macro: buffer bb, tile base column jj0
  #define STAGE(bb, jj0) do {                                                     \
    _Pragma("unroll")                                                             \
    for (int k = 0; k < 4; ++k){                                                  \
      int r = k*16 + hb_r0;                                                       \
      int sp = hb_s ^ (r & 7);                                                    \
      gload_lds16(hBp + (size_t)((jj0) + r) * H_ + sp*8,                          \
                  &hbt[bb][0][0] + (k*8192 + wid*1024)/2);                        \
    }                                                                             \
    _Pragma("unroll")                                                             \
    for (int k = 0; k < 4; ++k){                                                  \
      int r = k*64 + vt_r0;                                                       \
      int sp = vt_s ^ (r & 7);                                                    \
      gload_lds16(vTp + (size_t)r * L_ + (jj0) + sp*8,                            \
                  &vtl[bb][0][0] + (k*8192 + wid*1024)/2);                        \
    }                                                                             \
  } while(0)

  STAGE(0, 0);
  __syncthreads();

  for (int jt = 0; jt < NT; ++jt){
    const int j0 = jt * TJ;
    const int cur = jt & 1;
    if (jt + 1 < NT) STAGE(cur ^ 1, j0 + TJ);

    // mask terms for this tile's 4 col-groups
    float mm[4];
    #pragma unroll
    for (int jj = 0; jj < 4; ++jj)
      mm[jj] = (mp[j0 + jj*16 + p] > 0) ? 0.f : -1e9f;

    // ---- QK: P[16 rows][64 cols]
    f32x4 accp[4];
    #pragma unroll
    for (int jj = 0; jj < 4; ++jj) accp[jj] = (f32x4){0.f,0.f,0.f,0.f};
    __builtin_amdgcn_s_setprio(1);
    #pragma unroll
    for (int kk = 0; kk < 8; ++kk){
      #pragma unroll
      for (int jj = 0; jj < 4; ++jj){
        int r = jj*16 + p;
        int sp = (kk*4 + q) ^ (r & 7);
        bf16x8 bfr = *(const bf16x8*)(&hbt[cur][r][sp*8]);
        accp[jj] = MFMA(af[kk], bfr, accp[jj]);
      }
    }
    __builtin_amdgcn_s_setprio(0);

    // ---- mask + tile max
    float tmax[4];
    #pragma unroll
    for (int r = 0; r < 4; ++r){
      accp[0][r] += mm[0]; accp[1][r] += mm[1];
      accp[2][r] += mm[2]; accp[3][r] += mm[3];
      tmax[r] = fmaxf(fmaxf(accp[0][r], accp[1][r]), fmaxf(accp[2][r], accp[3][r]));
    }
    #pragma unroll
    for (int off = 1; off < 16; off <<= 1)
      #pragma unroll
      for (int r = 0; r < 4; ++r)
        tmax[r] = fmaxf(tmax[r], __shfl_xor(tmax[r], off, 64));

    // ---- online update with defer-rescale (THR = 8)
    int need = 0;
    #pragma unroll
    for (int r = 0; r < 4; ++r) need |= (tmax[r] > m_run[r] + 8.f) ? 1 : 0;
    if (__any(need)){
      float fsc[4];
      #pragma unroll
      for (int r = 0; r < 4; ++r){
        float mn = fmaxf(m_run[r], tmax[r]);
        fsc[r] = __expf(m_run[r] - mn);
        s_run[r] *= fsc[r];
        m_run[r] = mn;
      }
      #pragma unroll
      for (int n = 0; n < 16; ++n)
        #pragma unroll
        for (int r = 0; r < 4; ++r)
          acc[n][r] *= fsc[r];
    }

    // ---- weights -> bf16 -> per-wave wtile
    #pragma unroll
    for (int jj = 0; jj < 4; ++jj)
      #pragma unroll
      for (int r = 0; r < 4; ++r){
        float w = __expf(accp[jj][r] - m_run[r]);
        s_run[r] += w;
        wtile[wid][q*4 + r][jj*16 + p] = f2bf(w);
      }
    bf16x8 wf0 = *(const bf16x8*)(&wtile[wid][p][q*8]);
    bf16x8 wf1 = *(const bf16x8*)(&wtile[wid][p][32 + q*8]);

    // ---- PV: acc += W @ V
    __builtin_amdgcn_s_setprio(1);
    #pragma unroll
    for (int n = 0; n < 16; ++n){
      int r0 = n*16 + p;
      int s0 = (0*4 + q) ^ (r0 & 7);
      int s1 = (1*4 + q) ^ (r0 & 7);
      bf16x8 vf0 = *(const bf16x8*)(&vtl[cur][r0][s0*8]);
      bf16x8 vf1 = *(const bf16x8*)(&vtl[cur][r0][s1*8]);
      acc[n] = MFMA(wf0, vf0, acc[n]);
      acc[n] = MFMA(wf1, vf1, acc[n]);
    }
    __builtin_amdgcn_s_setprio(0);

    __syncthreads();
  }
  #undef STAGE

  // ---- finish: reduce s over the 16 col-lanes, normalize, store
  #pragma unroll
  for (int off = 1; off < 16; off <<= 1)
    #pragma unroll
    for (int r = 0; r < 4; ++r)
      s_run[r] += __shfl_xor(s_run[r], off, 64);
  float invS[4];
  #pragma unroll
  for (int r = 0; r < 4; ++r) invS[r] = 1.0f / s_run[r];

  #pragma unroll
  for (int n = 0; n < 16; ++n)
    #pragma unroll
    for (int r = 0; r < 4; ++r){
      int row = i0 + wid*16 + q*4 + r;
      outp[(size_t)row * D_ + n*16 + p] = acc[n][r] * invS[r];
    }
}

extern "C" void kernel_launch(void* const* d_in, const int* in_sizes, int n_in,
                              void* d_out, int out_size, void* d_ws, size_t ws_size,
                              hipStream_t stream) {
  const float* a      = (const float*)d_in[0];
  const float* b      = (const float*)d_in[1];
  const int*   mask_a = (const int*)d_in[2];
  const int*   mask_b = (const int*)d_in[3];
  const float* a_v    = (const float*)d_in[4];
  const float* a_g    = (const float*)d_in[5];
  const float* a_bias = (const float*)d_in[6];
  const float* b_v    = (const float*)d_in[7];
  const float* b_g    = (const float*)d_in[8];
  const float* b_bias = (const float*)d_in[9];
  const float* tau    = (const float*)d_in[10];

  float* out = (float*)d_out;

  char* ws = (char*)d_ws;
  const size_t SZ_W  = (size_t)H_ * D_ * 2;        // 128 KB
  const size_t SZ_H  = (size_t)B_ * L_ * H_ * 2;   // 8 MB
  unsigned short* wa = (unsigned short*)(ws);
  unsigned short* wb = (unsigned short*)(ws + SZ_W);
  unsigned short* ha = (unsigned short*)(ws + 2*SZ_W);
  unsigned short* hb = (unsigned short*)(ws + 2*SZ_W + SZ_H);
  unsigned short* aT = (unsigned short*)(ws + 2*SZ_W + 2*SZ_H);
  unsigned short* bT = (unsigned short*)(ws + 2*SZ_W + 3*SZ_H);
  size_t need = 2*SZ_W + 4*SZ_H;
  if (ws_size < need) return;

  // 1. normalized weights (bf16)
  wnorm_kernel<<<H_, 256, 0, stream>>>(a_v, a_g, wa);
  wnorm_kernel<<<H_, 256, 0, stream>>>(b_v, b_g, wb);

  // 2. transposed bf16 copies of a, b  ([B][D][L])
  {
    dim3 g(L_/32, D_/32, B_), blk(32, 8);
    transpose_kernel<<<g, blk, 0, stream>>>(a, aT);
    transpose_kernel<<<g, blk, 0, stream>>>(b, bT);
  }

  // 3. ha = bf16(tau*relu(a@wa^T + bias)), hb = bf16(relu(b@wb^T + bias))
  {
    dim3 g((B_*L_)/64, H_/64);
    hgemm_kernel<<<g, 256, 0, stream>>>(a, wa, a_bias, tau, 1, ha);
    hgemm_kernel<<<g, 256, 0, stream>>>(b, wb, b_bias, tau, 0, hb);
  }

  // 4. fused flash alignment, both directions (256 blocks = 1/CU, XCD-affine)
  {
    flash_kernel<<<dim3((L_/BM) * B_ * 2), 512, 0, stream>>>(
        ha, hb, aT, bT, mask_a, mask_b, out);
  }
}